// Round 2
// baseline (246.331 us; speedup 1.0000x reference)
//
#include <hip/hip_runtime.h>
#include <cstdint>
#include <cstddef>

// ---------------------------------------------------------------------------
// SelfAttention block on MI355X (gfx950), bf16 MFMA pipeline:
//   convert(fp32->bf16) + mask bitpack -> proj3 GEMM (qh,kh,vh) -> flash-attn
//   -> out GEMM
// Shapes: B=2, S=2048, E=1024, H=16, D=64; GEMMs are [4096,1024]x[1024,1024]^T
// ---------------------------------------------------------------------------

typedef uint16_t u16;
typedef unsigned long long u64;
using bf16x8 = __attribute__((ext_vector_type(8))) __bf16;
using f32x4  = __attribute__((ext_vector_type(4))) float;
using u16x8  = __attribute__((ext_vector_type(8))) uint16_t;
using u16x4  = __attribute__((ext_vector_type(4))) uint16_t;

#define S_LEN 2048
#define EMB   1024
#define NHEAD 16
#define HDIM  64
#define BATCH 2
#define MROWS (BATCH * S_LEN)   // 4096 GEMM rows
#define NBITW (BATCH * S_LEN * (S_LEN / 64))  // 131072 u64 mask words

// fp32 -> bf16 RNE
__device__ __forceinline__ u16 f2bf(float f) {
  uint32_t u = __float_as_uint(f);
  u += 0x7FFFu + ((u >> 16) & 1u);
  return (u16)(u >> 16);
}

// async global->LDS 16B copy (dest = wave-uniform base + lane*16, HW rule)
__device__ __forceinline__ void async16(void* lds, const void* g) {
  __builtin_amdgcn_global_load_lds(
      (const __attribute__((address_space(1))) void*)g,
      (__attribute__((address_space(3))) void*)lds, 16, 0, 0);
}

// ---------------------------------------------------------------------------
// Kernel 0: mask bit-pack, storage-width agnostic.
// Detects byte-bool (word0 == 0x01010101 for all-true) vs 4-byte elements
// (int32 / float32: nonzero test). bits[i] packs mask elements [64i, 64i+64).
// ---------------------------------------------------------------------------
__global__ __launch_bounds__(256) void mask_compact(const uint32_t* __restrict__ m,
                                                    u64* __restrict__ bits) {
  const int i = blockIdx.x * 256 + threadIdx.x;
  if (i >= NBITW) return;
  const bool bytew = (m[0] == 0x01010101u);
  u64 b = 0;
  if (bytew) {
    const uint32_t* src = m + (size_t)i * 16;  // 64 bytes = 16 words
#pragma unroll
    for (int w = 0; w < 16; ++w) {
      const uint32_t v = src[w];
#pragma unroll
      for (int j = 0; j < 4; ++j)
        b |= (u64)(((v >> (8 * j)) & 0xFFu) != 0u) << (w * 4 + j);
    }
  } else {
    const uint32_t* src = m + (size_t)i * 64;  // 64 4-byte elements
#pragma unroll
    for (int j = 0; j < 64; ++j) b |= (u64)(src[j] != 0u) << j;
  }
  bits[i] = b;
}

// ---------------------------------------------------------------------------
// Kernel 1: fp32 -> bf16 conversion for 7 tensors (q,k,v, Wq,Wk,Wv,Wo)
// ---------------------------------------------------------------------------
struct ConvArgs {
  const float* src[7];
  u16* dst[7];
  int n4[7];   // element count / 4
};

__global__ __launch_bounds__(256) void convert_bf16(ConvArgs a) {
  const int j = blockIdx.y;
  const float4* s = (const float4*)a.src[j];
  u16* d = a.dst[j];
  const int n4 = a.n4[j];
  for (int i = blockIdx.x * 256 + threadIdx.x; i < n4; i += gridDim.x * 256) {
    float4 v = s[i];
    u16x4 o = { f2bf(v.x), f2bf(v.y), f2bf(v.z), f2bf(v.w) };
    *(u16x4*)(d + (size_t)i * 4) = o;
  }
}

// ---------------------------------------------------------------------------
// m97-style bf16 GEMM: C[m,n] = (sum_k A[m,k]*W[n,k] + bias[n]) * scale
// A: [4096,1024] bf16 row-major, W: [1024,1024] bf16 row-major (torch Linear)
// 128x128 tile, BK=32, 256 threads (4 waves, 2x2 of 64x64), global_load_lds.
// ---------------------------------------------------------------------------
template <typename OutT>
__device__ __forceinline__ void gemm_body(const u16* __restrict__ A,
                                          const u16* __restrict__ W,
                                          const float* __restrict__ bias,
                                          OutT* __restrict__ C, float scale) {
  constexpr int K = 1024, N = 1024;
  __shared__ alignas(16) u16 As[128 * 32];
  __shared__ alignas(16) u16 Bs[128 * 32];
  const int t = threadIdx.x;
  const int wave = t >> 6, lane = t & 63;
  const int wr = wave >> 1, wc = wave & 1;
  const int m0 = blockIdx.y * 128, n0 = blockIdx.x * 128;
  f32x4 acc[4][4] = {};
  // staging: linear LDS, row = t/4 (64B rows), chunk = t%4
  const int srow = wave * 16 + (lane >> 2);
  const int soff = (lane & 3) * 8;
  const u16* gA = A + (size_t)(m0 + srow) * K + soff;
  const u16* gB = W + (size_t)(n0 + srow) * K + soff;
  u16* lA = As + wave * 512;
  u16* lB = Bs + wave * 512;
  const int fo = (lane >> 4) * 8;   // k-offset within BK for fragments
  const int fr = lane & 15;         // fragment row

  for (int kt = 0; kt < K; kt += 32) {
    async16(lA,        gA + kt);
    async16(lA + 2048, gA + (size_t)64 * K + kt);
    async16(lB,        gB + kt);
    async16(lB + 2048, gB + (size_t)64 * K + kt);
    __syncthreads();
    bf16x8 af[4], bfr[4];
#pragma unroll
    for (int i = 0; i < 4; ++i)
      af[i] = *(const bf16x8*)(As + (wr * 64 + i * 16 + fr) * 32 + fo);
#pragma unroll
    for (int i = 0; i < 4; ++i)
      bfr[i] = *(const bf16x8*)(Bs + (wc * 64 + i * 16 + fr) * 32 + fo);
#pragma unroll
    for (int mi = 0; mi < 4; ++mi)
#pragma unroll
      for (int ni = 0; ni < 4; ++ni)
        acc[mi][ni] = __builtin_amdgcn_mfma_f32_16x16x32_bf16(af[mi], bfr[ni],
                                                              acc[mi][ni], 0, 0, 0);
    __syncthreads();
  }
  // epilogue: C/D layout col=lane&15, row=(lane>>4)*4+reg (m89-verified)
  const int r0 = (lane >> 4) * 4;
#pragma unroll
  for (int mi = 0; mi < 4; ++mi) {
    const int rowb = m0 + wr * 64 + mi * 16 + r0;
#pragma unroll
    for (int ni = 0; ni < 4; ++ni) {
      const int col = n0 + wc * 64 + ni * 16 + fr;
      const float bv = bias[col];
#pragma unroll
      for (int r = 0; r < 4; ++r) {
        float v = (acc[mi][ni][r] + bv) * scale;
        if constexpr (sizeof(OutT) == 2)
          C[(size_t)(rowb + r) * N + col] = f2bf(v);
        else
          C[(size_t)(rowb + r) * N + col] = v;
      }
    }
  }
}

struct ProjArgs {
  const u16* A[3];
  const u16* W[3];
  const float* bias[3];
  u16* C[3];
  float scale[3];
};

__global__ __launch_bounds__(256) void gemm_proj3(ProjArgs p) {
  const int z = blockIdx.z;
  gemm_body<u16>(p.A[z], p.W[z], p.bias[z], p.C[z], p.scale[z]);
}

__global__ __launch_bounds__(256) void gemm_out(const u16* __restrict__ A,
                                                const u16* __restrict__ W,
                                                const float* __restrict__ bias,
                                                float* __restrict__ C) {
  gemm_body<float>(A, W, bias, C, 1.0f);
}

// ---------------------------------------------------------------------------
// Kernel 3: flash attention.
// Grid (S/64, B*H); block 256 = 4 waves; wave owns 16 q rows.
// qh is pre-scaled by log2(e)/32 -> logits are base-2; online softmax in exp2.
// K tile [64 key][64 d] LDS, XOR-swizzled via pre-swizzled global source.
// V tile stored transposed [64 d][64 key], XOR-swizzled, reg-staged.
// P re-layout (C-frag -> A-frag) through per-wave swizzled LDS buffer.
// Mask consumed as bit-packed u64 words (see mask_compact).
// Swizzle rule everywhere: byte_pos = linear_byte ^ ((row&7)<<4)  (G4 / m214)
// ---------------------------------------------------------------------------
__global__ __launch_bounds__(256) void attn_fa(const u16* __restrict__ Qh,
                                               const u16* __restrict__ Kh,
                                               const u16* __restrict__ Vh,
                                               const u64* __restrict__ mbits,
                                               u16* __restrict__ O) {
  __shared__ alignas(16) u16 Kt[64 * 64];
  __shared__ alignas(16) u16 Vt[64 * 64];
  __shared__ alignas(16) u16 Pb[4][16 * 64];
  const int t = threadIdx.x, wave = t >> 6, lane = t & 63;
  const int b = blockIdx.y >> 4, h = blockIdx.y & 15;
  const int q0 = blockIdx.x * 64;
  const int qw = q0 + wave * 16;
  const int fr = lane & 15, fh = lane >> 4;

  // Q A-fragments, held in registers for the whole kv loop
  const size_t qoff = (size_t)(b * S_LEN + qw + fr) * EMB + h * HDIM + fh * 8;
  const bf16x8 qf0 = *(const bf16x8*)(Qh + qoff);
  const bf16x8 qf1 = *(const bf16x8*)(Qh + qoff + 32);

  f32x4 o[4] = {};
  float mrow[4] = {-3.0e38f, -3.0e38f, -3.0e38f, -3.0e38f};
  float lrow[4] = {0.f, 0.f, 0.f, 0.f};

  const int krow0 = wave * 8 + (lane >> 3);  // K staging row (call 0)
  const int kch = lane & 7;                  // K staging chunk
  u16* ldsK = Kt + wave * 512;
  const int vdg = t & 7, vkp = t >> 3;       // V staging: 8 d-groups x 32 key-pairs
  const int vk0 = vkp * 2, vd0 = vdg * 8;
  const u16* kbase = Kh + (size_t)(b * S_LEN) * EMB + h * HDIM;
  const u16* vbase = Vh + (size_t)(b * S_LEN) * EMB + h * HDIM;
  // mask bitmap: row r's kv-tile word at mbits[(b*S + r)*32 + kv/64]
  const u64* mrow_base = mbits + ((size_t)b * S_LEN + qw) * 32;

  for (int kv = 0; kv < S_LEN; kv += 64) {
    __syncthreads();  // previous tile's LDS reads complete
    {  // stage K via global_load_lds, source pre-swizzled (rule #21)
      const int r0 = krow0, r1 = krow0 + 32;
      async16(ldsK,        kbase + (size_t)(kv + r0) * EMB + ((kch ^ (r0 & 7)) * 8));
      async16(ldsK + 2048, kbase + (size_t)(kv + r1) * EMB + ((kch ^ (r1 & 7)) * 8));
    }
    {  // stage V transposed + swizzled (reg-staged, conflict-free b32 writes)
      const u16* vs = vbase + (size_t)(kv + vk0) * EMB + vd0;
      u16x8 va = *(const u16x8*)vs;
      u16x8 vb = *(const u16x8*)(vs + EMB);
#pragma unroll
      for (int j = 0; j < 8; ++j) {
        const int d = vd0 + j;
        const uint32_t val = (uint32_t)va[j] | ((uint32_t)vb[j] << 16);
        *(uint32_t*)((char*)Vt + (d * 128 + ((vkp * 4) ^ ((d & 7) << 4)))) = val;
      }
    }
    // mask fast-path probe: 16 q rows x 64 keys, one u64 per row
    const u64 mw = mrow_base[(size_t)(lane & 15) * 32 + (kv >> 6)];
    __syncthreads();

    // QK^T: e[nt] = 16x16 tile, rows=q, cols=key
    f32x4 e[4];
#pragma unroll
    for (int nt = 0; nt < 4; ++nt) {
      const int kr = nt * 16 + fr;
      const char* kRow = (const char*)Kt + kr * 128;
      bf16x8 k0 = *(const bf16x8*)(kRow + ((fh ^ (kr & 7)) << 4));
      bf16x8 k1 = *(const bf16x8*)(kRow + (((4 + fh) ^ (kr & 7)) << 4));
      f32x4 z = {0.f, 0.f, 0.f, 0.f};
      z = __builtin_amdgcn_mfma_f32_16x16x32_bf16(qf0, k0, z, 0, 0, 0);
      e[nt] = __builtin_amdgcn_mfma_f32_16x16x32_bf16(qf1, k1, z, 0, 0, 0);
    }

    // mask: fast all-ones check per wave strip; slow path per bit
    if (!__all((int)(mw == ~0ull))) {
#pragma unroll
      for (int r = 0; r < 4; ++r) {
        const u64 rb = mrow_base[(size_t)(fh * 4 + r) * 32 + (kv >> 6)];
#pragma unroll
        for (int nt = 0; nt < 4; ++nt)
          if (!((rb >> (nt * 16 + fr)) & 1ull)) e[nt][r] = -1.0e20f;
      }
    }

    // online softmax (base-2 domain; scale already folded into qh)
    float tmax[4];
#pragma unroll
    for (int r = 0; r < 4; ++r)
      tmax[r] = fmaxf(fmaxf(e[0][r], e[1][r]), fmaxf(e[2][r], e[3][r]));
#pragma unroll
    for (int off = 1; off < 16; off <<= 1)
#pragma unroll
      for (int r = 0; r < 4; ++r)
        tmax[r] = fmaxf(tmax[r], __shfl_xor(tmax[r], off));
    float alpha[4], rsum[4];
#pragma unroll
    for (int r = 0; r < 4; ++r) {
      const float mn = fmaxf(mrow[r], tmax[r]);
      alpha[r] = exp2f(mrow[r] - mn);
      mrow[r] = mn;
      rsum[r] = 0.f;
    }
#pragma unroll
    for (int nt = 0; nt < 4; ++nt)
#pragma unroll
      for (int r = 0; r < 4; ++r) {
        const float p = exp2f(e[nt][r] - mrow[r]);
        e[nt][r] = p;
        rsum[r] += p;
      }
#pragma unroll
    for (int off = 1; off < 16; off <<= 1)
#pragma unroll
      for (int r = 0; r < 4; ++r)
        rsum[r] += __shfl_xor(rsum[r], off);
#pragma unroll
    for (int r = 0; r < 4; ++r)
      lrow[r] = lrow[r] * alpha[r] + rsum[r];
#pragma unroll
    for (int dt = 0; dt < 4; ++dt) {
      o[dt][0] *= alpha[0]; o[dt][1] *= alpha[1];
      o[dt][2] *= alpha[2]; o[dt][3] *= alpha[3];
    }

    // P (C-frag) -> per-wave LDS (bf16, swizzled) -> A-frag
    char* pw = (char*)Pb[wave];
#pragma unroll
    for (int nt = 0; nt < 4; ++nt)
#pragma unroll
      for (int r = 0; r < 4; ++r) {
        const int ql = fh * 4 + r;
        const int cb = (nt * 16 + fr) * 2;
        *(u16*)(pw + ql * 128 + (cb ^ ((ql & 7) << 4))) = f2bf(e[nt][r]);
      }
    bf16x8 pf0, pf1;
    {
      const char* pr = pw + fr * 128;
      pf0 = *(const bf16x8*)(pr + ((fh ^ (fr & 7)) << 4));
      pf1 = *(const bf16x8*)(pr + (((4 + fh) ^ (fr & 7)) << 4));
    }
    // PV: o[dt] += P @ V   (A=P rows q, B=V^T tile gives (k=key, n=d))
#pragma unroll
    for (int dt = 0; dt < 4; ++dt) {
      const int d = dt * 16 + fr;
      const char* vr = (const char*)Vt + d * 128;
      bf16x8 v0 = *(const bf16x8*)(vr + ((fh ^ (d & 7)) << 4));
      bf16x8 v1 = *(const bf16x8*)(vr + (((4 + fh) ^ (d & 7)) << 4));
      o[dt] = __builtin_amdgcn_mfma_f32_16x16x32_bf16(pf0, v0, o[dt], 0, 0, 0);
      o[dt] = __builtin_amdgcn_mfma_f32_16x16x32_bf16(pf1, v1, o[dt], 0, 0, 0);
    }
  }

  // epilogue: O = o / l, bf16, layout [b,s,h,d]
  float inv[4];
#pragma unroll
  for (int r = 0; r < 4; ++r) inv[r] = 1.0f / lrow[r];
  u16* ob = O + (size_t)(b * S_LEN + qw) * EMB + h * HDIM;
#pragma unroll
  for (int dt = 0; dt < 4; ++dt) {
    const int d = dt * 16 + fr;
#pragma unroll
    for (int r = 0; r < 4; ++r)
      ob[(size_t)(fh * 4 + r) * EMB + d] = f2bf(o[dt][r] * inv[r]);
  }
}

// ---------------------------------------------------------------------------
// launch
// ---------------------------------------------------------------------------
extern "C" void kernel_launch(void* const* d_in, const int* in_sizes, int n_in,
                              void* d_out, int out_size, void* d_ws, size_t ws_size,
                              hipStream_t stream) {
  const float* v_in = (const float*)d_in[0];
  const float* k_in = (const float*)d_in[1];
  const float* q_in = (const float*)d_in[2];
  const uint32_t* mask = (const uint32_t*)d_in[3];
  const float* Wv = (const float*)d_in[4];
  const float* bv = (const float*)d_in[5];
  const float* Wk = (const float*)d_in[6];
  const float* bk = (const float*)d_in[7];
  const float* Wq = (const float*)d_in[8];
  const float* bq = (const float*)d_in[9];
  const float* Wo = (const float*)d_in[10];
  const float* bo = (const float*)d_in[11];

  char* ws = (char*)d_ws;
  const size_t SZX = (size_t)MROWS * EMB * 2;  // 8 MB per [4096,1024] bf16
  const size_t SZW = (size_t)EMB * EMB * 2;    // 2 MB per weight bf16
  u16* qh  = (u16*)(ws);
  u16* kh  = (u16*)(ws + SZX);
  u16* vh  = (u16*)(ws + 2 * SZX);
  u16* Obf = (u16*)(ws + 3 * SZX);
  u16* Wqb = (u16*)(ws + 4 * SZX);
  u16* Wkb = (u16*)(ws + 4 * SZX + SZW);
  u16* Wvb = (u16*)(ws + 4 * SZX + 2 * SZW);
  u16* Wob = (u16*)(ws + 4 * SZX + 3 * SZW);
  u16* qbf = (u16*)(ws + 4 * SZX + 4 * SZW);
  u16* kbf = (u16*)(ws + 5 * SZX + 4 * SZW);
  u16* vbf = (u16*)(ws + 6 * SZX + 4 * SZW);
  u64* mbits = (u64*)(ws + 7 * SZX + 4 * SZW);
  // total ws use: 7*SZX + 4*SZW + 1MB = 68.2 MB

  mask_compact<<<dim3(NBITW / 256), 256, 0, stream>>>(mask, mbits);

  ConvArgs ca;
  ca.src[0] = q_in; ca.dst[0] = qbf; ca.n4[0] = MROWS * EMB / 4;
  ca.src[1] = k_in; ca.dst[1] = kbf; ca.n4[1] = MROWS * EMB / 4;
  ca.src[2] = v_in; ca.dst[2] = vbf; ca.n4[2] = MROWS * EMB / 4;
  ca.src[3] = Wq;   ca.dst[3] = Wqb; ca.n4[3] = EMB * EMB / 4;
  ca.src[4] = Wk;   ca.dst[4] = Wkb; ca.n4[4] = EMB * EMB / 4;
  ca.src[5] = Wv;   ca.dst[5] = Wvb; ca.n4[5] = EMB * EMB / 4;
  ca.src[6] = Wo;   ca.dst[6] = Wob; ca.n4[6] = EMB * EMB / 4;
  convert_bf16<<<dim3(256, 7), 256, 0, stream>>>(ca);

  ProjArgs pa;
  // scale on Q projection folds softmax 1/sqrt(1024) AND log2(e) for exp2-domain
  const float qscale = 1.4426950408889634f / 32.0f;
  pa.A[0] = qbf; pa.W[0] = Wqb; pa.bias[0] = bq; pa.C[0] = qh; pa.scale[0] = qscale;
  pa.A[1] = kbf; pa.W[1] = Wkb; pa.bias[1] = bk; pa.C[1] = kh; pa.scale[1] = 1.0f;
  pa.A[2] = vbf; pa.W[2] = Wvb; pa.bias[2] = bv; pa.C[2] = vh; pa.scale[2] = 1.0f;
  gemm_proj3<<<dim3(8, 32, 3), 256, 0, stream>>>(pa);

  attn_fa<<<dim3(S_LEN / 64, BATCH * NHEAD), 256, 0, stream>>>(qh, kh, vh, mbits, Obf);

  gemm_out<<<dim3(8, 32), 256, 0, stream>>>(Obf, Wob, bo, (float*)d_out);
}

// Round 3
// 157.416 us; speedup vs baseline: 1.5648x; 1.5648x over previous
//
#include <hip/hip_runtime.h>
#include <cstdint>
#include <cstddef>

// ---------------------------------------------------------------------------
// SelfAttention block on MI355X (gfx950), bf16 MFMA pipeline:
//   mask bitpack + convert(fp32->bf16) -> proj3 GEMM (qh,kh,vh) -> flash-attn
//   (32x32 swapped-operand, in-register softmax) -> out GEMM
// Shapes: B=2, S=2048, E=1024, H=16, D=64; GEMMs are [4096,1024]x[1024,1024]^T
// ---------------------------------------------------------------------------

typedef uint16_t u16;
typedef uint32_t u32;
typedef unsigned long long u64;
using bf16x8 = __attribute__((ext_vector_type(8))) __bf16;
using bf16x2 = __attribute__((ext_vector_type(2))) __bf16;
using f32x4  = __attribute__((ext_vector_type(4))) float;
using f32x16 = __attribute__((ext_vector_type(16))) float;
using u16x8  = __attribute__((ext_vector_type(8))) uint16_t;
using u16x4  = __attribute__((ext_vector_type(4))) uint16_t;
using u32x4  = __attribute__((ext_vector_type(4))) uint32_t;

#define S_LEN 2048
#define EMB   1024
#define NHEAD 16
#define HDIM  64
#define BATCH 2
#define MROWS (BATCH * S_LEN)   // 4096 GEMM rows
#define NBITW (BATCH * S_LEN * (S_LEN / 64))  // 131072 u64 mask words

// fp32 -> bf16 RNE
__device__ __forceinline__ u16 f2bf(float f) {
  uint32_t u = __float_as_uint(f);
  u += 0x7FFFu + ((u >> 16) & 1u);
  return (u16)(u >> 16);
}

__device__ __forceinline__ float fexp2(float x) {
#if __has_builtin(__builtin_amdgcn_exp2f)
  return __builtin_amdgcn_exp2f(x);
#else
  return exp2f(x);
#endif
}

// pack two f32 -> u32 of 2 bf16 (lo = a, hi = b); compiler may fuse to cvt_pk
__device__ __forceinline__ u32 packbf(float a, float b) {
  bf16x2 v = { (__bf16)a, (__bf16)b };
  return __builtin_bit_cast(u32, v);
}

// async global->LDS 16B copy (dest = wave-uniform base + lane*16, HW rule)
__device__ __forceinline__ void async16(void* lds, const void* g) {
  __builtin_amdgcn_global_load_lds(
      (const __attribute__((address_space(1))) void*)g,
      (__attribute__((address_space(3))) void*)lds, 16, 0, 0);
}

// ---------------------------------------------------------------------------
// Kernel 0: mask bit-pack, storage-width agnostic (byte-bool vs 4-byte).
// ---------------------------------------------------------------------------
__global__ __launch_bounds__(256) void mask_compact(const uint32_t* __restrict__ m,
                                                    u64* __restrict__ bits) {
  const int i = blockIdx.x * 256 + threadIdx.x;
  if (i >= NBITW) return;
  const bool bytew = (m[0] == 0x01010101u);
  u64 b = 0;
  if (bytew) {
    const uint32_t* src = m + (size_t)i * 16;  // 64 bytes = 16 words
#pragma unroll
    for (int w = 0; w < 16; ++w) {
      const uint32_t v = src[w];
#pragma unroll
      for (int j = 0; j < 4; ++j)
        b |= (u64)(((v >> (8 * j)) & 0xFFu) != 0u) << (w * 4 + j);
    }
  } else {
    const uint32_t* src = m + (size_t)i * 64;  // 64 4-byte elements
#pragma unroll
    for (int j = 0; j < 64; ++j) b |= (u64)(src[j] != 0u) << j;
  }
  bits[i] = b;
}

// ---------------------------------------------------------------------------
// Kernel 1: fp32 -> bf16 conversion for 7 tensors (q,k,v, Wq,Wk,Wv,Wo)
// ---------------------------------------------------------------------------
struct ConvArgs {
  const float* src[7];
  u16* dst[7];
  int n4[7];
};

__global__ __launch_bounds__(256) void convert_bf16(ConvArgs a) {
  const int j = blockIdx.y;
  const float4* s = (const float4*)a.src[j];
  u16* d = a.dst[j];
  const int n4 = a.n4[j];
  for (int i = blockIdx.x * 256 + threadIdx.x; i < n4; i += gridDim.x * 256) {
    float4 v = s[i];
    u16x4 o = { f2bf(v.x), f2bf(v.y), f2bf(v.z), f2bf(v.w) };
    *(u16x4*)(d + (size_t)i * 4) = o;
  }
}

// ---------------------------------------------------------------------------
// m97-style bf16 GEMM (unchanged from round 2): 128x128 tile, BK=32, 4 waves.
// ---------------------------------------------------------------------------
template <typename OutT>
__device__ __forceinline__ void gemm_body(const u16* __restrict__ A,
                                          const u16* __restrict__ W,
                                          const float* __restrict__ bias,
                                          OutT* __restrict__ C, float scale) {
  constexpr int K = 1024, N = 1024;
  __shared__ alignas(16) u16 As[128 * 32];
  __shared__ alignas(16) u16 Bs[128 * 32];
  const int t = threadIdx.x;
  const int wave = t >> 6, lane = t & 63;
  const int wr = wave >> 1, wc = wave & 1;
  const int m0 = blockIdx.y * 128, n0 = blockIdx.x * 128;
  f32x4 acc[4][4] = {};
  const int srow = wave * 16 + (lane >> 2);
  const int soff = (lane & 3) * 8;
  const u16* gA = A + (size_t)(m0 + srow) * K + soff;
  const u16* gB = W + (size_t)(n0 + srow) * K + soff;
  u16* lA = As + wave * 512;
  u16* lB = Bs + wave * 512;
  const int fo = (lane >> 4) * 8;
  const int fr = lane & 15;

  for (int kt = 0; kt < K; kt += 32) {
    async16(lA,        gA + kt);
    async16(lA + 2048, gA + (size_t)64 * K + kt);
    async16(lB,        gB + kt);
    async16(lB + 2048, gB + (size_t)64 * K + kt);
    __syncthreads();
    bf16x8 af[4], bfr[4];
#pragma unroll
    for (int i = 0; i < 4; ++i)
      af[i] = *(const bf16x8*)(As + (wr * 64 + i * 16 + fr) * 32 + fo);
#pragma unroll
    for (int i = 0; i < 4; ++i)
      bfr[i] = *(const bf16x8*)(Bs + (wc * 64 + i * 16 + fr) * 32 + fo);
#pragma unroll
    for (int mi = 0; mi < 4; ++mi)
#pragma unroll
      for (int ni = 0; ni < 4; ++ni)
        acc[mi][ni] = __builtin_amdgcn_mfma_f32_16x16x32_bf16(af[mi], bfr[ni],
                                                              acc[mi][ni], 0, 0, 0);
    __syncthreads();
  }
  const int r0 = (lane >> 4) * 4;
#pragma unroll
  for (int mi = 0; mi < 4; ++mi) {
    const int rowb = m0 + wr * 64 + mi * 16 + r0;
#pragma unroll
    for (int ni = 0; ni < 4; ++ni) {
      const int col = n0 + wc * 64 + ni * 16 + fr;
      const float bv = bias[col];
#pragma unroll
      for (int r = 0; r < 4; ++r) {
        float v = (acc[mi][ni][r] + bv) * scale;
        if constexpr (sizeof(OutT) == 2)
          C[(size_t)(rowb + r) * N + col] = f2bf(v);
        else
          C[(size_t)(rowb + r) * N + col] = v;
      }
    }
  }
}

struct ProjArgs {
  const u16* A[3];
  const u16* W[3];
  const float* bias[3];
  u16* C[3];
  float scale[3];
};

__global__ __launch_bounds__(256) void gemm_proj3(ProjArgs p) {
  const int z = blockIdx.z;
  gemm_body<u16>(p.A[z], p.W[z], p.bias[z], p.C[z], p.scale[z]);
}

__global__ __launch_bounds__(256) void gemm_out(const u16* __restrict__ A,
                                                const u16* __restrict__ W,
                                                const float* __restrict__ bias,
                                                float* __restrict__ C) {
  gemm_body<float>(A, W, bias, C, 1.0f);
}

// ---------------------------------------------------------------------------
// Kernel 3: flash attention, m214-style (32x32 MFMA, swapped operands).
// Grid (S/128, B*H); block 256 = 4 waves; wave owns 32 q rows (q = lane&31).
// QK^T swapped: S^T = mfma(K, Q): lane holds P[key=crow(r,hi)][q=lane&31],
//   crow(r,hi) = (r&3) + 8*(r>>2) + 4*hi,  hi = lane>>5.  (m74/m101 layout)
// Softmax fully lane-local (one q-row per lane) + shfl_xor(32) combine.
// PV swapped: O^T = mfma(V^T, P): P B-frags built in-register via
//   16 packbf + 16 shfl_xor(32) + selects (T12's shfl form).
// K LDS [64key][64d] XOR-swizzled via pre-swizzled global src (rule #21);
// V LDS transposed [64d][64key] XOR-swizzled, reg-staged (T14 issue-early).
// Double-buffered, one barrier per tile. Defer-max (T13, THR=8 base-2).
// ---------------------------------------------------------------------------
__global__ __launch_bounds__(256, 2) void attn_fa(const u16* __restrict__ Qh,
                                                  const u16* __restrict__ Kh,
                                                  const u16* __restrict__ Vh,
                                                  const u64* __restrict__ mbits,
                                                  u16* __restrict__ O) {
  __shared__ alignas(16) u16 Kt[2][64 * 64];
  __shared__ alignas(16) u16 Vt[2][64 * 64];
  const int t = threadIdx.x, wave = t >> 6, lane = t & 63;
  const int b = blockIdx.y >> 4, h = blockIdx.y & 15;
  const int ql = lane & 31;            // q within wave's 32-row strip
  const int hi = lane >> 5;
  const int qrow = blockIdx.x * 128 + wave * 32 + ql;  // q row in batch b

  // Q B-fragments (registers, whole kernel): d = dk*16 + hi*8 + 0..7
  const u16* qbase = Qh + (size_t)(b * S_LEN + qrow) * EMB + h * HDIM + hi * 8;
  bf16x8 qf[4];
#pragma unroll
  for (int dk = 0; dk < 4; ++dk)
    qf[dk] = *(const bf16x8*)(qbase + dk * 16);

  // K staging geometry (global_load_lds, 2 issues of 32 rows)
  const int srow = t >> 3;             // 0..31
  const int schunk = t & 7;
  const u16* kbase = Kh + (size_t)(b * S_LEN) * EMB + h * HDIM;
  const u16* vbase = Vh + (size_t)(b * S_LEN) * EMB + h * HDIM;
  // V staging: thread loads 2 keys x 8 d, writes 8 u32 (key-pairs) transposed
  const int vdg = t & 7, vkp = t >> 3;
  const int vd0 = vdg * 8, vk0 = vkp * 2;

  u16x8 va, vb;
  {  // stage tile 0
    async16(&Kt[0][0] + wave * 512,
            kbase + (size_t)srow * EMB + ((schunk ^ (srow & 7)) * 8));
    async16(&Kt[0][0] + 2048 + wave * 512,
            kbase + (size_t)(srow + 32) * EMB + ((schunk ^ ((srow + 32) & 7)) * 8));
    const u16* vs = vbase + (size_t)vk0 * EMB + vd0;
    va = *(const u16x8*)vs;
    vb = *(const u16x8*)(vs + EMB);
  }
#pragma unroll
  for (int j = 0; j < 8; ++j) {
    const int d = vd0 + j;
    const u32 val = (u32)va[j] | ((u32)vb[j] << 16);
    *(u32*)((char*)&Vt[0][0] + (d * 128 + ((vkp * 4) ^ ((d & 7) << 4)))) = val;
  }
  __syncthreads();

  f32x16 o[2] = {};
  float mreg = -1.0e30f, lloc = 0.f;
  const u64* mword = mbits + (size_t)(b * S_LEN + qrow) * 32;

  for (int kt = 0; kt < 32; ++kt) {
    const int cur = kt & 1, nxt = cur ^ 1;
    if (kt < 31) {  // issue-early staging for tile kt+1 (T14)
      const int kvn = (kt + 1) * 64;
      async16(&Kt[nxt][0] + wave * 512,
              kbase + (size_t)(kvn + srow) * EMB + ((schunk ^ (srow & 7)) * 8));
      async16(&Kt[nxt][0] + 2048 + wave * 512,
              kbase + (size_t)(kvn + srow + 32) * EMB +
                  ((schunk ^ ((srow + 32) & 7)) * 8));
      const u16* vs = vbase + (size_t)(kvn + vk0) * EMB + vd0;
      va = *(const u16x8*)vs;
      vb = *(const u16x8*)(vs + EMB);
    }

    // ---- QK^T (swapped): s[kb] = K-block kb^T rows x Q cols ----
    f32x16 s[2] = {};
#pragma unroll
    for (int kb = 0; kb < 2; ++kb) {
      const int key = kb * 32 + ql;
      const char* kRow = (const char*)&Kt[cur][0] + key * 128;
#pragma unroll
      for (int dk = 0; dk < 4; ++dk) {
        const bf16x8 kf =
            *(const bf16x8*)(kRow + ((dk * 32 + hi * 16) ^ ((key & 7) << 4)));
        s[kb] = __builtin_amdgcn_mfma_f32_32x32x16_bf16(kf, qf[dk], s[kb], 0, 0, 0);
      }
    }

    // ---- mask (bit-packed; fast path = all-true word) ----
    const u64 mw = mword[kt];
    if (!__all((int)(mw == ~0ull))) {
#pragma unroll
      for (int kb = 0; kb < 2; ++kb)
#pragma unroll
        for (int r = 0; r < 16; ++r) {
          const int key = 32 * kb + (r & 3) + 8 * (r >> 2) + 4 * hi;
          if (!((mw >> key) & 1ull)) s[kb][r] = -1.0e20f;
        }
    }

    // ---- online softmax, lane-local (q = ql), defer-max (THR=8) ----
    float tm = s[0][0];
#pragma unroll
    for (int kb = 0; kb < 2; ++kb)
#pragma unroll
      for (int r = 0; r < 16; ++r) tm = fmaxf(tm, s[kb][r]);
    tm = fmaxf(tm, __shfl_xor(tm, 32));
    if (!__all((int)(tm <= mreg + 8.0f))) {
      const float mn = fmaxf(mreg, tm);
      const float al = fexp2(mreg - mn);
      mreg = mn;
      lloc *= al;
#pragma unroll
      for (int dB = 0; dB < 2; ++dB)
#pragma unroll
        for (int r = 0; r < 16; ++r) o[dB][r] *= al;
    }
    float ts = 0.f;
#pragma unroll
    for (int kb = 0; kb < 2; ++kb)
#pragma unroll
      for (int r = 0; r < 16; ++r) {
        const float p = fexp2(s[kb][r] - mreg);
        s[kb][r] = p;
        ts += p;
      }
    lloc += ts;

    // ---- P -> B-fragments (in-register exchange across hi halves) ----
    // w[kb][i] packs keys 32kb + 8*(i>>1) + 4*hi_src + 2*(i&1) + {0,1}
    u32 w[2][8], pw[2][8];
#pragma unroll
    for (int kb = 0; kb < 2; ++kb)
#pragma unroll
      for (int i = 0; i < 8; ++i) {
        w[kb][i] = packbf(s[kb][2 * i], s[kb][2 * i + 1]);
        pw[kb][i] = (u32)__shfl_xor((int)w[kb][i], 32);
      }
    const bool hiL = (hi != 0);
    bf16x8 pf[4];
#pragma unroll
    for (int ks = 0; ks < 4; ++ks) {
      const int kb = ks >> 1, iL = (ks & 1) * 4;
      // frag(ks) keys: ks*16 + hi*8 + 0..7
      const u32 a0 = hiL ? pw[kb][iL + 2] : w[kb][iL + 0];
      const u32 a1 = hiL ? pw[kb][iL + 3] : w[kb][iL + 1];
      const u32 a2 = hiL ? w[kb][iL + 2] : pw[kb][iL + 0];
      const u32 a3 = hiL ? w[kb][iL + 3] : pw[kb][iL + 1];
      const u32x4 uv = {a0, a1, a2, a3};
      pf[ks] = __builtin_bit_cast(bf16x8, uv);
    }

    // ---- PV (swapped): o[dB] += V^T-block x P ----
#pragma unroll
    for (int dB = 0; dB < 2; ++dB) {
      const int d = dB * 32 + ql;
      const char* vRow = (const char*)&Vt[cur][0] + d * 128;
#pragma unroll
      for (int ks = 0; ks < 4; ++ks) {
        const bf16x8 vf =
            *(const bf16x8*)(vRow + ((ks * 32 + hi * 16) ^ ((d & 7) << 4)));
        o[dB] = __builtin_amdgcn_mfma_f32_32x32x16_bf16(vf, pf[ks], o[dB], 0, 0, 0);
      }
    }

    // ---- write-late V staging for tile kt+1, single barrier ----
    if (kt < 31) {
#pragma unroll
      for (int j = 0; j < 8; ++j) {
        const int d = vd0 + j;
        const u32 val = (u32)va[j] | ((u32)vb[j] << 16);
        *(u32*)((char*)&Vt[nxt][0] + (d * 128 + ((vkp * 4) ^ ((d & 7) << 4)))) = val;
      }
    }
    __syncthreads();
  }

  // ---- epilogue: O^T[d][q] -> O[b, q, h, d], scaled by 1/l ----
  const float inv = 1.0f / (lloc + __shfl_xor(lloc, 32));
  u16* ob = O + (size_t)(b * S_LEN + qrow) * EMB + h * HDIM;
#pragma unroll
  for (int dB = 0; dB < 2; ++dB)
#pragma unroll
    for (int rr = 0; rr < 4; ++rr) {
      u16x4 st;
#pragma unroll
      for (int m = 0; m < 4; ++m) st[m] = f2bf(o[dB][rr * 4 + m] * inv);
      *(u16x4*)(ob + dB * 32 + rr * 8 + hi * 4) = st;
    }
}

// ---------------------------------------------------------------------------
// launch
// ---------------------------------------------------------------------------
extern "C" void kernel_launch(void* const* d_in, const int* in_sizes, int n_in,
                              void* d_out, int out_size, void* d_ws, size_t ws_size,
                              hipStream_t stream) {
  const float* v_in = (const float*)d_in[0];
  const float* k_in = (const float*)d_in[1];
  const float* q_in = (const float*)d_in[2];
  const uint32_t* mask = (const uint32_t*)d_in[3];
  const float* Wv = (const float*)d_in[4];
  const float* bv = (const float*)d_in[5];
  const float* Wk = (const float*)d_in[6];
  const float* bk = (const float*)d_in[7];
  const float* Wq = (const float*)d_in[8];
  const float* bq = (const float*)d_in[9];
  const float* Wo = (const float*)d_in[10];
  const float* bo = (const float*)d_in[11];

  char* ws = (char*)d_ws;
  const size_t SZX = (size_t)MROWS * EMB * 2;  // 8 MB per [4096,1024] bf16
  const size_t SZW = (size_t)EMB * EMB * 2;    // 2 MB per weight bf16
  u16* qh  = (u16*)(ws);
  u16* kh  = (u16*)(ws + SZX);
  u16* vh  = (u16*)(ws + 2 * SZX);
  u16* Obf = (u16*)(ws + 3 * SZX);
  u16* Wqb = (u16*)(ws + 4 * SZX);
  u16* Wkb = (u16*)(ws + 4 * SZX + SZW);
  u16* Wvb = (u16*)(ws + 4 * SZX + 2 * SZW);
  u16* Wob = (u16*)(ws + 4 * SZX + 3 * SZW);
  u16* qbf = (u16*)(ws + 4 * SZX + 4 * SZW);
  u16* kbf = (u16*)(ws + 5 * SZX + 4 * SZW);
  u16* vbf = (u16*)(ws + 6 * SZX + 4 * SZW);
  u64* mbits = (u64*)(ws + 7 * SZX + 4 * SZW);

  mask_compact<<<dim3(NBITW / 256), 256, 0, stream>>>(mask, mbits);

  ConvArgs ca;
  ca.src[0] = q_in; ca.dst[0] = qbf; ca.n4[0] = MROWS * EMB / 4;
  ca.src[1] = k_in; ca.dst[1] = kbf; ca.n4[1] = MROWS * EMB / 4;
  ca.src[2] = v_in; ca.dst[2] = vbf; ca.n4[2] = MROWS * EMB / 4;
  ca.src[3] = Wq;   ca.dst[3] = Wqb; ca.n4[3] = EMB * EMB / 4;
  ca.src[4] = Wk;   ca.dst[4] = Wkb; ca.n4[4] = EMB * EMB / 4;
  ca.src[5] = Wv;   ca.dst[5] = Wvb; ca.n4[5] = EMB * EMB / 4;
  ca.src[6] = Wo;   ca.dst[6] = Wob; ca.n4[6] = EMB * EMB / 4;
  convert_bf16<<<dim3(256, 7), 256, 0, stream>>>(ca);

  ProjArgs pa;
  // Q-proj scale folds softmax 1/sqrt(1024) AND log2(e) (exp2 domain)
  const float qscale = 1.4426950408889634f / 32.0f;
  pa.A[0] = qbf; pa.W[0] = Wqb; pa.bias[0] = bq; pa.C[0] = qh; pa.scale[0] = qscale;
  pa.A[1] = kbf; pa.W[1] = Wkb; pa.bias[1] = bk; pa.C[1] = kh; pa.scale[1] = 1.0f;
  pa.A[2] = vbf; pa.W[2] = Wvb; pa.bias[2] = bv; pa.C[2] = vh; pa.scale[2] = 1.0f;
  gemm_proj3<<<dim3(8, 32, 3), 256, 0, stream>>>(pa);

  attn_fa<<<dim3(S_LEN / 128, BATCH * NHEAD), 256, 0, stream>>>(qh, kh, vh, mbits, Obf);

  gemm_out<<<dim3(8, 32), 256, 0, stream>>>(Obf, Wob, bo, (float*)d_out);
}

// Round 5
// 142.325 us; speedup vs baseline: 1.7308x; 1.1060x over previous
//
#include <hip/hip_runtime.h>
#include <cstdint>
#include <cstddef>

// ---------------------------------------------------------------------------
// SelfAttention block on MI355X (gfx950), bf16 MFMA pipeline:
//   mask bitpack + convert(fp32->bf16) -> proj3 GEMM (qh,kh,vh) -> flash-attn
//   (32x32 swapped-operand, in-register softmax, permlane P-exchange) -> out GEMM
// Shapes: B=2, S=2048, E=1024, H=16, D=64; GEMMs are [4096,1024]x[1024,1024]^T
// ---------------------------------------------------------------------------

typedef uint16_t u16;
typedef uint32_t u32;
typedef unsigned long long u64;
using bf16x8 = __attribute__((ext_vector_type(8))) __bf16;
using bf16x2 = __attribute__((ext_vector_type(2))) __bf16;
using f32x4  = __attribute__((ext_vector_type(4))) float;
using f32x16 = __attribute__((ext_vector_type(16))) float;
using u16x8  = __attribute__((ext_vector_type(8))) uint16_t;
using u16x4  = __attribute__((ext_vector_type(4))) uint16_t;
using u32x4  = __attribute__((ext_vector_type(4))) uint32_t;

#define S_LEN 2048
#define EMB   1024
#define NHEAD 16
#define HDIM  64
#define BATCH 2
#define MROWS (BATCH * S_LEN)   // 4096 GEMM rows
#define NBITW (BATCH * S_LEN * (S_LEN / 64))  // 131072 u64 mask words

// fp32 -> bf16 RNE
__device__ __forceinline__ u16 f2bf(float f) {
  uint32_t u = __float_as_uint(f);
  u += 0x7FFFu + ((u >> 16) & 1u);
  return (u16)(u >> 16);
}

__device__ __forceinline__ float fexp2(float x) {
#if __has_builtin(__builtin_amdgcn_exp2f)
  return __builtin_amdgcn_exp2f(x);
#else
  return exp2f(x);
#endif
}

// pack two f32 -> u32 of 2 bf16 (lo = a, hi = b)
__device__ __forceinline__ u32 packbf(float a, float b) {
  bf16x2 v = { (__bf16)a, (__bf16)b };
  return __builtin_bit_cast(u32, v);
}

// v_permlane32_swap: a'[l<32]=a[l], a'[l>=32]=b[l-32];
//                    b'[l<32]=a[l+32], b'[l>=32]=b[l].
// ONLY safe when a and b are independent computations (never a copy pair —
// the register allocator may coalesce provably-equal "+v" operands, turning
// the swap into a self-swap; cost us round 4).
__device__ __forceinline__ void plswap(u32& a, u32& b) {
  asm volatile("v_permlane32_swap_b32 %0, %1" : "+v"(a), "+v"(b));
}

// async global->LDS 16B copy (dest = wave-uniform base + lane*16, HW rule)
__device__ __forceinline__ void async16(void* lds, const void* g) {
  __builtin_amdgcn_global_load_lds(
      (const __attribute__((address_space(1))) void*)g,
      (__attribute__((address_space(3))) void*)lds, 16, 0, 0);
}

// ---------------------------------------------------------------------------
// Kernel 0: mask bit-pack, storage-width agnostic (byte-bool vs 4-byte).
// ---------------------------------------------------------------------------
__global__ __launch_bounds__(256) void mask_compact(const uint32_t* __restrict__ m,
                                                    u64* __restrict__ bits) {
  const int i = blockIdx.x * 256 + threadIdx.x;
  if (i >= NBITW) return;
  const bool bytew = (m[0] == 0x01010101u);
  u64 b = 0;
  if (bytew) {
    const uint32_t* src = m + (size_t)i * 16;  // 64 bytes = 16 words
#pragma unroll
    for (int w = 0; w < 16; ++w) {
      const uint32_t v = src[w];
#pragma unroll
      for (int j = 0; j < 4; ++j)
        b |= (u64)(((v >> (8 * j)) & 0xFFu) != 0u) << (w * 4 + j);
    }
  } else {
    const uint32_t* src = m + (size_t)i * 64;  // 64 4-byte elements
#pragma unroll
    for (int j = 0; j < 64; ++j) b |= (u64)(src[j] != 0u) << j;
  }
  bits[i] = b;
}

// ---------------------------------------------------------------------------
// Kernel 1: fp32 -> bf16 conversion for 7 tensors (q,k,v, Wq,Wk,Wv,Wo)
// ---------------------------------------------------------------------------
struct ConvArgs {
  const float* src[7];
  u16* dst[7];
  int n4[7];
};

__global__ __launch_bounds__(256) void convert_bf16(ConvArgs a) {
  const int j = blockIdx.y;
  const float4* s = (const float4*)a.src[j];
  u16* d = a.dst[j];
  const int n4 = a.n4[j];
  for (int i = blockIdx.x * 256 + threadIdx.x; i < n4; i += gridDim.x * 256) {
    float4 v = s[i];
    u16x4 o = { f2bf(v.x), f2bf(v.y), f2bf(v.z), f2bf(v.w) };
    *(u16x4*)(d + (size_t)i * 4) = o;
  }
}

// ---------------------------------------------------------------------------
// m97-style bf16 GEMM, parameterized tile: C = (A @ W^T + bias) * scale
// BM x BN tile, BK=32, 256 threads = 4 waves (2x2), per-wave FM x FN frags.
// ---------------------------------------------------------------------------
template <int BM, int BN, int FM, int FN, typename OutT>
__device__ __forceinline__ void gemm_body(const u16* __restrict__ A,
                                          const u16* __restrict__ W,
                                          const float* __restrict__ bias,
                                          OutT* __restrict__ C, float scale) {
  constexpr int K = 1024, N = 1024;
  __shared__ alignas(16) u16 As[BM * 32];
  __shared__ alignas(16) u16 Bs[BN * 32];
  const int t = threadIdx.x;
  const int wave = t >> 6, lane = t & 63;
  const int wr = wave >> 1, wc = wave & 1;
  const int m0 = blockIdx.y * BM, n0 = blockIdx.x * BN;
  f32x4 acc[FM][FN] = {};
  const int srow = wave * 16 + (lane >> 2);  // 0..63 across block
  const int soff = (lane & 3) * 8;
  const u16* gA = A + (size_t)(m0 + srow) * K + soff;
  const u16* gB = W + (size_t)(n0 + srow) * K + soff;
  u16* lA = As + wave * 512;
  u16* lB = Bs + wave * 512;
  const int fo = (lane >> 4) * 8;
  const int fr = lane & 15;

  for (int kt = 0; kt < K; kt += 32) {
#pragma unroll
    for (int a = 0; a < BM / 64; ++a)
      async16(lA + a * 2048, gA + (size_t)(a * 64) * K + kt);
#pragma unroll
    for (int a = 0; a < BN / 64; ++a)
      async16(lB + a * 2048, gB + (size_t)(a * 64) * K + kt);
    __syncthreads();
    bf16x8 af[FM], bfr[FN];
#pragma unroll
    for (int i = 0; i < FM; ++i)
      af[i] = *(const bf16x8*)(As + (wr * (FM * 16) + i * 16 + fr) * 32 + fo);
#pragma unroll
    for (int i = 0; i < FN; ++i)
      bfr[i] = *(const bf16x8*)(Bs + (wc * (FN * 16) + i * 16 + fr) * 32 + fo);
#pragma unroll
    for (int mi = 0; mi < FM; ++mi)
#pragma unroll
      for (int ni = 0; ni < FN; ++ni)
        acc[mi][ni] = __builtin_amdgcn_mfma_f32_16x16x32_bf16(af[mi], bfr[ni],
                                                              acc[mi][ni], 0, 0, 0);
    __syncthreads();
  }
  const int r0 = (lane >> 4) * 4;
#pragma unroll
  for (int mi = 0; mi < FM; ++mi) {
    const int rowb = m0 + wr * (FM * 16) + mi * 16 + r0;
#pragma unroll
    for (int ni = 0; ni < FN; ++ni) {
      const int col = n0 + wc * (FN * 16) + ni * 16 + fr;
      const float bv = bias[col];
#pragma unroll
      for (int r = 0; r < 4; ++r) {
        float v = (acc[mi][ni][r] + bv) * scale;
        if constexpr (sizeof(OutT) == 2)
          C[(size_t)(rowb + r) * N + col] = f2bf(v);
        else
          C[(size_t)(rowb + r) * N + col] = v;
      }
    }
  }
}

struct ProjArgs {
  const u16* A[3];
  const u16* W[3];
  const float* bias[3];
  u16* C[3];
  float scale[3];
};

__global__ __launch_bounds__(256) void gemm_proj3(ProjArgs p) {
  const int z = blockIdx.z;
  gemm_body<128, 128, 4, 4, u16>(p.A[z], p.W[z], p.bias[z], p.C[z], p.scale[z]);
}

// out GEMM: 64x128 tile -> grid (8,64) = 512 blocks (2/CU) for occupancy
__global__ __launch_bounds__(256) void gemm_out(const u16* __restrict__ A,
                                                const u16* __restrict__ W,
                                                const float* __restrict__ bias,
                                                float* __restrict__ C) {
  gemm_body<64, 128, 2, 4, float>(A, W, bias, C, 1.0f);
}

// ---------------------------------------------------------------------------
// Kernel 3: flash attention, m214-style (32x32 MFMA, swapped operands).
// Grid (S/128, B*H); block 256 = 4 waves; wave owns 32 q rows (q = lane&31).
// QK^T swapped: S^T = mfma(K, Q); softmax lane-local; PV swapped:
// O^T = mfma(V^T, P) with P B-frags built via v_permlane32_swap (T12).
// Scalar cross-half combines (tm, lsum) use __shfl_xor(.,32) — NOT plswap
// (identical-value operand pair can be register-coalesced into a self-swap).
// LDS swizzle (both K and V): granule(row, g) = g ^ ((row + (row>>3)) & 7)
//   - K: DMA-write linear (conflict-free), source pre-swizzled (rule #21)
//   - V: reg-staged transpose; write banks are a bijection of lane -> 0 conflicts
// Double-buffered, one barrier/tile. Defer-max (T13, THR=8 base-2).
// ---------------------------------------------------------------------------
__global__ __launch_bounds__(256, 2) void attn_fa(const u16* __restrict__ Qh,
                                                  const u16* __restrict__ Kh,
                                                  const u16* __restrict__ Vh,
                                                  const u64* __restrict__ mbits,
                                                  u16* __restrict__ O) {
  __shared__ alignas(16) u16 Kt[2][64 * 64];
  __shared__ alignas(16) u16 Vt[2][64 * 64];
  const int t = threadIdx.x, wave = t >> 6, lane = t & 63;
  const int b = blockIdx.y >> 4, h = blockIdx.y & 15;
  const int ql = lane & 31;            // q within wave's 32-row strip
  const int hi = lane >> 5;
  const int qrow = blockIdx.x * 128 + wave * 32 + ql;

  // Q B-fragments (registers, whole kernel): d = dk*16 + hi*8 + 0..7
  const u16* qbase = Qh + (size_t)(b * S_LEN + qrow) * EMB + h * HDIM + hi * 8;
  bf16x8 qf[4];
#pragma unroll
  for (int dk = 0; dk < 4; ++dk)
    qf[dk] = *(const bf16x8*)(qbase + dk * 16);

  // K staging geometry (global_load_lds, 2 issues of 32 rows each)
  const int srow = t >> 3;             // 0..31
  const int schunk = t & 7;
  const int fk0 = (srow + (srow >> 3)) & 7;
  const int fk1 = (srow + 32 + ((srow + 32) >> 3)) & 7;
  const u16* kbase = Kh + (size_t)(b * S_LEN) * EMB + h * HDIM;
  const u16* vbase = Vh + (size_t)(b * S_LEN) * EMB + h * HDIM;
  // V staging: thread loads 2 keys x 8 d, writes 8 u32 (key-pairs) transposed
  const int vdg = t & 7, vkp = t >> 3;         // vkp = key-pair 0..31
  const int vd0 = vdg * 8, vk0 = vkp * 2;
  const int vg_hi = (vkp >> 2) & 7, vg_lo = (vkp & 3) * 4;

  u16x8 va, vb;
  {  // stage tile 0
    async16(&Kt[0][0] + wave * 512,
            kbase + (size_t)srow * EMB + ((schunk ^ fk0) * 8));
    async16(&Kt[0][0] + 2048 + wave * 512,
            kbase + (size_t)(srow + 32) * EMB + ((schunk ^ fk1) * 8));
    const u16* vs = vbase + (size_t)vk0 * EMB + vd0;
    va = *(const u16x8*)vs;
    vb = *(const u16x8*)(vs + EMB);
  }
#pragma unroll
  for (int j = 0; j < 8; ++j) {
    const int d = vd0 + j;
    const int fd = (d + (d >> 3)) & 7;
    const u32 val = (u32)va[j] | ((u32)vb[j] << 16);
    *(u32*)((char*)&Vt[0][0] + (d * 128 + ((vg_hi ^ fd) << 4) + vg_lo)) = val;
  }
  __syncthreads();

  f32x16 o[2] = {};
  float mreg = -1.0e30f, lloc = 0.f;
  const u64* mword = mbits + (size_t)(b * S_LEN + qrow) * 32;

  for (int kt = 0; kt < 32; ++kt) {
    const int cur = kt & 1, nxt = cur ^ 1;
    if (kt < 31) {  // issue-early staging for tile kt+1 (T14)
      const int kvn = (kt + 1) * 64;
      async16(&Kt[nxt][0] + wave * 512,
              kbase + (size_t)(kvn + srow) * EMB + ((schunk ^ fk0) * 8));
      async16(&Kt[nxt][0] + 2048 + wave * 512,
              kbase + (size_t)(kvn + srow + 32) * EMB + ((schunk ^ fk1) * 8));
      const u16* vs = vbase + (size_t)(kvn + vk0) * EMB + vd0;
      va = *(const u16x8*)vs;
      vb = *(const u16x8*)(vs + EMB);
    }

    // ---- QK^T (swapped): s[kb] = K-block kb^T rows x Q cols ----
    f32x16 s[2] = {};
#pragma unroll
    for (int kb = 0; kb < 2; ++kb) {
      const int key = kb * 32 + ql;
      const int fkk = (key + (key >> 3)) & 7;
      const char* kRow = (const char*)&Kt[cur][0] + key * 128;
#pragma unroll
      for (int dk = 0; dk < 4; ++dk) {
        const bf16x8 kf =
            *(const bf16x8*)(kRow + (((dk * 2 + hi) ^ fkk) << 4));
        s[kb] = __builtin_amdgcn_mfma_f32_32x32x16_bf16(kf, qf[dk], s[kb], 0, 0, 0);
      }
    }

    // ---- mask (bit-packed; fast path = all-true word) ----
    const u64 mw = mword[kt];
    if (!__all((int)(mw == ~0ull))) {
#pragma unroll
      for (int kb = 0; kb < 2; ++kb)
#pragma unroll
        for (int r = 0; r < 16; ++r) {
          const int key = 32 * kb + (r & 3) + 8 * (r >> 2) + 4 * hi;
          if (!((mw >> key) & 1ull)) s[kb][r] = -1.0e20f;
        }
    }

    // ---- online softmax, lane-local (q = ql), defer-max (THR=8) ----
    float tm = s[0][0];
#pragma unroll
    for (int kb = 0; kb < 2; ++kb)
#pragma unroll
      for (int r = 0; r < 16; ++r) tm = fmaxf(tm, s[kb][r]);
    tm = fmaxf(tm, __shfl_xor(tm, 32));   // cross-half max (proven path)
    if (!__all((int)(tm <= mreg + 8.0f))) {
      const float mn = fmaxf(mreg, tm);
      const float al = fexp2(mreg - mn);
      mreg = mn;
      lloc *= al;
#pragma unroll
      for (int dB = 0; dB < 2; ++dB)
#pragma unroll
        for (int r = 0; r < 16; ++r) o[dB][r] *= al;
    }
    float ts = 0.f;
#pragma unroll
    for (int kb = 0; kb < 2; ++kb)
#pragma unroll
      for (int r = 0; r < 16; ++r) {
        const float p = fexp2(s[kb][r] - mreg);
        s[kb][r] = p;
        ts += p;
      }
    lloc += ts;

    // ---- P -> B-fragments via permlane32_swap (T12) ----
    // w words are independent packbf results (no coalescing hazard).
    bf16x8 pf[4];
#pragma unroll
    for (int kb = 0; kb < 2; ++kb) {
      u32 w0 = packbf(s[kb][0], s[kb][1]);
      u32 w1 = packbf(s[kb][2], s[kb][3]);
      u32 w2 = packbf(s[kb][4], s[kb][5]);
      u32 w3 = packbf(s[kb][6], s[kb][7]);
      u32 w4 = packbf(s[kb][8], s[kb][9]);
      u32 w5 = packbf(s[kb][10], s[kb][11]);
      u32 w6 = packbf(s[kb][12], s[kb][13]);
      u32 w7 = packbf(s[kb][14], s[kb][15]);
      plswap(w0, w2);
      plswap(w1, w3);
      plswap(w4, w6);
      plswap(w5, w7);
      const u32x4 lo = {w0, w1, w2, w3};
      const u32x4 hi4 = {w4, w5, w6, w7};
      pf[kb * 2 + 0] = __builtin_bit_cast(bf16x8, lo);
      pf[kb * 2 + 1] = __builtin_bit_cast(bf16x8, hi4);
    }

    // ---- PV (swapped): o[dB] += V^T-block x P ----
#pragma unroll
    for (int dB = 0; dB < 2; ++dB) {
      const int d = dB * 32 + ql;
      const int fd = (d + (d >> 3)) & 7;
      const char* vRow = (const char*)&Vt[cur][0] + d * 128;
#pragma unroll
      for (int ks = 0; ks < 4; ++ks) {
        const bf16x8 vf =
            *(const bf16x8*)(vRow + (((ks * 2 + hi) ^ fd) << 4));
        o[dB] = __builtin_amdgcn_mfma_f32_32x32x16_bf16(vf, pf[ks], o[dB], 0, 0, 0);
      }
    }

    // ---- write-late V staging for tile kt+1, single barrier ----
    if (kt < 31) {
#pragma unroll
      for (int j = 0; j < 8; ++j) {
        const int d = vd0 + j;
        const int fd = (d + (d >> 3)) & 7;
        const u32 val = (u32)va[j] | ((u32)vb[j] << 16);
        *(u32*)((char*)&Vt[nxt][0] + (d * 128 + ((vg_hi ^ fd) << 4) + vg_lo)) = val;
      }
    }
    __syncthreads();
  }

  // ---- epilogue: O^T[d][q] -> O[b, q, h, d], scaled by 1/l ----
  const float inv = 1.0f / (lloc + __shfl_xor(lloc, 32));  // proven path
  u16* ob = O + (size_t)(b * S_LEN + qrow) * EMB + h * HDIM;
#pragma unroll
  for (int dB = 0; dB < 2; ++dB)
#pragma unroll
    for (int rr = 0; rr < 4; ++rr) {
      u16x4 st;
#pragma unroll
      for (int m = 0; m < 4; ++m) st[m] = f2bf(o[dB][rr * 4 + m] * inv);
      *(u16x4*)(ob + dB * 32 + rr * 8 + hi * 4) = st;
    }
}

// ---------------------------------------------------------------------------
// launch
// ---------------------------------------------------------------------------
extern "C" void kernel_launch(void* const* d_in, const int* in_sizes, int n_in,
                              void* d_out, int out_size, void* d_ws, size_t ws_size,
                              hipStream_t stream) {
  const float* v_in = (const float*)d_in[0];
  const float* k_in = (const float*)d_in[1];
  const float* q_in = (const float*)d_in[2];
  const uint32_t* mask = (const uint32_t*)d_in[3];
  const float* Wv = (const float*)d_in[4];
  const float* bv = (const float*)d_in[5];
  const float* Wk = (const float*)d_in[6];
  const float* bk = (const float*)d_in[7];
  const float* Wq = (const float*)d_in[8];
  const float* bq = (const float*)d_in[9];
  const float* Wo = (const float*)d_in[10];
  const float* bo = (const float*)d_in[11];

  char* ws = (char*)d_ws;
  const size_t SZX = (size_t)MROWS * EMB * 2;  // 8 MB per [4096,1024] bf16
  const size_t SZW = (size_t)EMB * EMB * 2;    // 2 MB per weight bf16
  u16* qh  = (u16*)(ws);
  u16* kh  = (u16*)(ws + SZX);
  u16* vh  = (u16*)(ws + 2 * SZX);
  u16* Obf = (u16*)(ws + 3 * SZX);
  u16* Wqb = (u16*)(ws + 4 * SZX);
  u16* Wkb = (u16*)(ws + 4 * SZX + SZW);
  u16* Wvb = (u16*)(ws + 4 * SZX + 2 * SZW);
  u16* Wob = (u16*)(ws + 4 * SZX + 3 * SZW);
  u16* qbf = (u16*)(ws + 4 * SZX + 4 * SZW);
  u16* kbf = (u16*)(ws + 5 * SZX + 4 * SZW);
  u16* vbf = (u16*)(ws + 6 * SZX + 4 * SZW);
  u64* mbits = (u64*)(ws + 7 * SZX + 4 * SZW);

  mask_compact<<<dim3(NBITW / 256), 256, 0, stream>>>(mask, mbits);

  ConvArgs ca;
  ca.src[0] = q_in; ca.dst[0] = qbf; ca.n4[0] = MROWS * EMB / 4;
  ca.src[1] = k_in; ca.dst[1] = kbf; ca.n4[1] = MROWS * EMB / 4;
  ca.src[2] = v_in; ca.dst[2] = vbf; ca.n4[2] = MROWS * EMB / 4;
  ca.src[3] = Wq;   ca.dst[3] = Wqb; ca.n4[3] = EMB * EMB / 4;
  ca.src[4] = Wk;   ca.dst[4] = Wkb; ca.n4[4] = EMB * EMB / 4;
  ca.src[5] = Wv;   ca.dst[5] = Wvb; ca.n4[5] = EMB * EMB / 4;
  ca.src[6] = Wo;   ca.dst[6] = Wob; ca.n4[6] = EMB * EMB / 4;
  convert_bf16<<<dim3(256, 7), 256, 0, stream>>>(ca);

  ProjArgs pa;
  // Q-proj scale folds softmax 1/sqrt(1024) AND log2(e) (exp2 domain)
  const float qscale = 1.4426950408889634f / 32.0f;
  pa.A[0] = qbf; pa.W[0] = Wqb; pa.bias[0] = bq; pa.C[0] = qh; pa.scale[0] = qscale;
  pa.A[1] = kbf; pa.W[1] = Wkb; pa.bias[1] = bk; pa.C[1] = kh; pa.scale[1] = 1.0f;
  pa.A[2] = vbf; pa.W[2] = Wvb; pa.bias[2] = bv; pa.C[2] = vh; pa.scale[2] = 1.0f;
  gemm_proj3<<<dim3(8, 32, 3), 256, 0, stream>>>(pa);

  attn_fa<<<dim3(S_LEN / 128, BATCH * NHEAD), 256, 0, stream>>>(qh, kh, vh, mbits, Obf);

  gemm_out<<<dim3(8, 64), 256, 0, stream>>>(Obf, Wob, bo, (float*)d_out);
}